// Round 5
// baseline (559.616 us; speedup 1.0000x reference)
//
#include <hip/hip_runtime.h>

// WaveletConv2D: 2-level DWT (8-tap), per-position 64x64 channel mix on the
// 4 level-2 subbands, then 2-level inverse DWT. All fp32.
// R7: DIAGNOSTIC ROUND. Source identical to R6; kernel_launch runs the whole
// (idempotent) chain TWICE. dur_us(R7) - dur_us(R6) = exact sum of kernel
// times, distinguishing "harness poison fills dominate dur_us" (~312us fixed,
// kernels ~71us -> predict ~455-500) from "kernels uniformly slow"
// (predict ~720-790). Chain is safe to re-run: dwt1 rewrites ll1 (aliased by
// res) before dwt2 re-reads it; all kernels are pure.

__constant__ float c_h0[8] = {0.0322231f, -0.01260397f, -0.09921954f, 0.2978578f,
                              0.80373875f, 0.49761867f, -0.02963553f, -0.07576571f};
__constant__ float c_h1[8] = {0.07576571f, -0.02963553f, -0.49761867f, 0.80373875f,
                              -0.2978578f, -0.09921954f, 0.01260397f, 0.0322231f};
// g0 = reverse(h0), g1 = reverse(h1)
__constant__ float c_g0[8] = {-0.07576571f, -0.02963553f, 0.49761867f, 0.80373875f,
                              0.2978578f, -0.09921954f, -0.01260397f, 0.0322231f};
__constant__ float c_g1[8] = {0.0322231f, 0.01260397f, -0.09921954f, -0.2978578f,
                              0.80373875f, -0.49761867f, -0.02963553f, 0.07576571f};

__device__ __forceinline__ float4 f4z() { return make_float4(0.f, 0.f, 0.f, 0.f); }
__device__ __forceinline__ float4 f4fma(float4 a, float w, float4 v) {
  a.x = fmaf(w, v.x, a.x); a.y = fmaf(w, v.y, a.y);
  a.z = fmaf(w, v.z, a.z); a.w = fmaf(w, v.w, a.w);
  return a;
}

// ---- Stage 1: x (32,128,128,64) -> ll1 (32,64,64,64), h0 x h0, stride 2, pad 3 ----
__global__ __launch_bounds__(256) void k_dwt1(const float* __restrict__ x,
                                              float* __restrict__ ll1) {
  __shared__ float4 sRow[2][40 * 17];
  int t = threadIdx.x;
  int c4 = t & 15;
  int owl = t >> 4;                 // 0..15
  int bid = blockIdx.x;             // b*32 + ohc*4 + owb
  int owb = bid & 3;
  int ohc = (bid >> 2) & 7;
  int b   = bid >> 5;
  int ow0 = owb * 16;
  int ow  = ow0 + owl;
  int oh0 = ohc * 8;
  int iw_start = 2 * ow0 - 3;       // global iw of LDS slot 0
  const float* xb = x + ((size_t)b << 20);

  auto stage2 = [&](int ih0) {
#pragma unroll
    for (int base = 0; base < 80; base += 16) {
      int item = base + owl;        // 0..79
      int rw   = item >= 40 ? 1 : 0;
      int iw_s = item - rw * 40;
      int ihc  = min(max(ih0 + rw, 0), 127);
      int iwc  = min(max(iw_start + iw_s, 0), 127);
      sRow[rw][iw_s * 17 + c4] =
          *(const float4*)(xb + (size_t)ihc * 8192 + (iwc << 6) + (c4 << 2));
    }
  };

  auto hrowL = [&](int rw, int ih) -> float4 {
    float4 r = f4z();
    if ((unsigned)ih >= 128u) return r;
#pragma unroll
    for (int j = 0; j < 8; ++j) {
      int iw  = 2 * ow - 3 + j;
      int iwc = min(max(iw, 0), 127);
      int iw_s = iwc - iw_start;    // in [0,39]
      float w = ((unsigned)iw < 128u) ? c_h0[j] : 0.f;
      r = f4fma(r, w, sRow[rw][iw_s * 17 + c4]);
    }
    return r;
  };

  float4 ring[8];
  int ihb = 2 * oh0 - 3;
#pragma unroll
  for (int pk = 0; pk < 3; ++pk) {
    stage2(ihb + 2 * pk);
    __syncthreads();
    ring[2 * pk]     = hrowL(0, ihb + 2 * pk);
    ring[2 * pk + 1] = hrowL(1, ihb + 2 * pk + 1);
    __syncthreads();
  }
  float* outp = ll1 + ((((size_t)b * 64 + oh0) * 64 + ow) << 6) + (c4 << 2);
#pragma unroll
  for (int oo = 0; oo < 8; ++oo) {
    stage2(ihb + 6);
    __syncthreads();
    ring[6] = hrowL(0, ihb + 6);
    ring[7] = hrowL(1, ihb + 7);
    float4 a = f4z();
#pragma unroll
    for (int i = 0; i < 8; ++i) a = f4fma(a, c_h0[i], ring[i]);
    *(float4*)(outp + oo * 4096) = a;
    __syncthreads();
#pragma unroll
    for (int k = 0; k < 6; ++k) ring[k] = ring[k + 2];
    ihb += 2;
  }
}

// ---- Stage 2: ll1 (32,64,64,64) -> 4 subbands (32,32,32,64) ----
__global__ __launch_bounds__(256) void k_dwt2(const float* __restrict__ ll1,
                                              float* __restrict__ subs) {
  __shared__ float4 sRow[2][40 * 17];
  int t = threadIdx.x;
  int c4 = t & 15;
  int owl = t >> 4;
  int bid = blockIdx.x;             // b*16 + ohc*2 + owb
  int owb = bid & 1;
  int ohc = (bid >> 1) & 7;
  int b   = bid >> 4;
  int ow0 = owb * 16;
  int ow  = ow0 + owl;
  int oh0 = ohc * 4;
  int iw_start = 2 * ow0 - 3;
  const float* lb = ll1 + ((size_t)b << 18);

  auto stage2 = [&](int ih0) {
#pragma unroll
    for (int base = 0; base < 80; base += 16) {
      int item = base + owl;
      int rw   = item >= 40 ? 1 : 0;
      int iw_s = item - rw * 40;
      int ihc  = min(max(ih0 + rw, 0), 63);
      int iwc  = min(max(iw_start + iw_s, 0), 63);
      sRow[rw][iw_s * 17 + c4] =
          *(const float4*)(lb + (size_t)ihc * 4096 + (iwc << 6) + (c4 << 2));
    }
  };

  auto hrow2L = [&](int rw, int ih, float4& rl, float4& rh) {
    rl = f4z(); rh = f4z();
    if ((unsigned)ih >= 64u) return;
#pragma unroll
    for (int j = 0; j < 8; ++j) {
      int iw  = 2 * ow - 3 + j;
      int iwc = min(max(iw, 0), 63);
      int iw_s = iwc - iw_start;
      bool ok = (unsigned)iw < 64u;
      float wl = ok ? c_h0[j] : 0.f;
      float wh = ok ? c_h1[j] : 0.f;
      float4 v = sRow[rw][iw_s * 17 + c4];
      rl = f4fma(rl, wl, v);
      rh = f4fma(rh, wh, v);
    }
  };

  float4 Rl[8], Rh[8];
  int ihb = 2 * oh0 - 3;
#pragma unroll
  for (int pk = 0; pk < 3; ++pk) {
    stage2(ihb + 2 * pk);
    __syncthreads();
    hrow2L(0, ihb + 2 * pk,     Rl[2 * pk],     Rh[2 * pk]);
    hrow2L(1, ihb + 2 * pk + 1, Rl[2 * pk + 1], Rh[2 * pk + 1]);
    __syncthreads();
  }
  float* outp = subs + ((((size_t)b * 32 + oh0) * 32 + ow) << 6) + (c4 << 2);
#pragma unroll
  for (int oo = 0; oo < 4; ++oo) {
    stage2(ihb + 6);
    __syncthreads();
    hrow2L(0, ihb + 6, Rl[6], Rh[6]);
    hrow2L(1, ihb + 7, Rl[7], Rh[7]);
    float4 a_ll = f4z(), a_lh = f4z(), a_hl = f4z(), a_hh = f4z();
#pragma unroll
    for (int i = 0; i < 8; ++i) {
      a_ll = f4fma(a_ll, c_h0[i], Rl[i]);
      a_lh = f4fma(a_lh, c_h0[i], Rh[i]);
      a_hl = f4fma(a_hl, c_h1[i], Rl[i]);
      a_hh = f4fma(a_hh, c_h1[i], Rh[i]);
    }
    float* o = outp + oo * 2048;
    *(float4*)(o)           = a_ll;
    *(float4*)(o + 2097152) = a_lh;
    *(float4*)(o + 4194304) = a_hl;
    *(float4*)(o + 6291456) = a_hh;
    __syncthreads();
#pragma unroll
    for (int k = 0; k < 6; ++k) { Rl[k] = Rl[k + 2]; Rh[k] = Rh[k + 2]; }
    ihb += 2;
  }
}

// ---- Weight transpose: W[i,o,h,w] (4096 x 1024) -> Wt[hw][io] (1024 x 4096) ----
__global__ __launch_bounds__(256) void k_transpose(const float* __restrict__ w1,
                                                   const float* __restrict__ w2,
                                                   const float* __restrict__ w3,
                                                   const float* __restrict__ w4,
                                                   float* __restrict__ wt) {
  __shared__ float tile[32][33];
  int s = blockIdx.z;
  const float* w = (s == 0) ? w1 : (s == 1) ? w2 : (s == 2) ? w3 : w4;
  int hw0 = blockIdx.x * 32;
  int io0 = blockIdx.y * 32;
  int tx = threadIdx.x & 31;
  int ty = threadIdx.x >> 5;  // 0..7
#pragma unroll
  for (int k = 0; k < 4; ++k) {
    int r = ty + k * 8;
    tile[r][tx] = w[(io0 + r) * 1024 + hw0 + tx];
  }
  __syncthreads();
  float* o = wt + (size_t)s * 4194304;
#pragma unroll
  for (int k = 0; k < 4; ++k) {
    int r = ty + k * 8;
    o[(hw0 + r) * 4096 + io0 + tx] = tile[tx][r];
  }
}

// ---- Einsum: out[b,p,o] = sum_i A[b,p,i] * W[i,o,p], per spatial position p ----
__global__ __launch_bounds__(256) void k_einsum(const float* __restrict__ subs,
                                               const float* __restrict__ w1,
                                               const float* __restrict__ w2,
                                               const float* __restrict__ w3,
                                               const float* __restrict__ w4,
                                               const float* __restrict__ wt,
                                               float* __restrict__ eout,
                                               int use_wt) {
  __shared__ float sW[4096];  // [i][o]
  __shared__ float sA[2048];  // [b][i]
  int p = blockIdx.x;   // 0..1023 = h*32+w
  int s = blockIdx.y;   // subband
  int t = threadIdx.x;
  const float* A = subs + (size_t)s * 2097152;
  if (use_wt) {
    const float* Wp = wt + (size_t)s * 4194304 + (size_t)p * 4096;
#pragma unroll
    for (int k = 0; k < 16; ++k) sW[t + 256 * k] = Wp[t + 256 * k];
  } else {
    const float* Ws = (s == 0) ? w1 : (s == 1) ? w2 : (s == 2) ? w3 : w4;
#pragma unroll
    for (int k = 0; k < 16; ++k) {
      int e = t + 256 * k;
      sW[e] = Ws[e * 1024 + p];
    }
  }
#pragma unroll
  for (int k = 0; k < 8; ++k) {
    int e = t + 256 * k;                       // e = b*64 + i
    sA[e] = A[(e >> 6) * 65536 + (p << 6) + (e & 63)];
  }
  __syncthreads();
  int o  = t & 63;
  int bg = t >> 6;  // 0..3, handles b = bg*8 .. bg*8+7
  float acc[8] = {0.f, 0.f, 0.f, 0.f, 0.f, 0.f, 0.f, 0.f};
  for (int i = 0; i < 64; ++i) {
    float wv = sW[(i << 6) + o];
#pragma unroll
    for (int k = 0; k < 8; ++k) acc[k] += sA[((bg * 8 + k) << 6) + i] * wv;
  }
  float* Oo = eout + (size_t)s * 2097152 + (p << 6) + o;
#pragma unroll
  for (int k = 0; k < 8; ++k) Oo[(bg * 8 + k) * 65536] = acc[k];
}

// ---- Inverse level 2: 4 subbands (32,32,32,64) -> res (32,64,64,64) ----
__global__ __launch_bounds__(256) void k_invres(const float* __restrict__ eout,
                                                float* __restrict__ res) {
  int t = threadIdx.x;
  int c4 = t & 15;
  int ql = t >> 4;
  int bid = blockIdx.x;             // b*8 + rc*2 + qb
  int qb = bid & 1;
  int rc = (bid >> 1) & 3;
  int b  = bid >> 3;
  int q  = qb * 16 + ql;
  int r0 = rc * 8;

  float4 Ae[4], Ao[4], Be[4], Bo[4];
  auto loadrow = [&](int m, float4& ae, float4& ao, float4& be, float4& bo) {
    ae = f4z(); ao = f4z(); be = f4z(); bo = f4z();
    if ((unsigned)m >= 32u) return;
    const float* base = eout + ((((size_t)b * 32 + m) * 32) << 6) + (c4 << 2);
    float4 vf[4], vl[4], vh[4], vv[4];
#pragma unroll
    for (int dn = -1; dn <= 2; ++dn) {
      int n = q + dn;
      int nc = min(max(n, 0), 31);
      const float* p = base + (nc << 6);
      vf[dn + 1] = *(const float4*)(p);
      vl[dn + 1] = *(const float4*)(p + 2097152);
      vh[dn + 1] = *(const float4*)(p + 4194304);
      vv[dn + 1] = *(const float4*)(p + 6291456);
    }
#pragma unroll
    for (int dn = -1; dn <= 2; ++dn) {
      int n = q + dn;
      bool ok = (unsigned)n < 32u;
      float g0e = ok ? c_g0[2 * dn + 3] : 0.f, g1e = ok ? c_g1[2 * dn + 3] : 0.f;
      float g0o = ok ? c_g0[2 * dn + 2] : 0.f, g1o = ok ? c_g1[2 * dn + 2] : 0.f;
      ae = f4fma(ae, g0e, vf[dn + 1]); ae = f4fma(ae, g1e, vl[dn + 1]);
      ao = f4fma(ao, g0o, vf[dn + 1]); ao = f4fma(ao, g1o, vl[dn + 1]);
      be = f4fma(be, g0e, vh[dn + 1]); be = f4fma(be, g1e, vv[dn + 1]);
      bo = f4fma(bo, g0o, vh[dn + 1]); bo = f4fma(bo, g1o, vv[dn + 1]);
    }
  };

#pragma unroll
  for (int k = 0; k < 3; ++k) loadrow(r0 - 1 + k, Ae[k], Ao[k], Be[k], Bo[k]);
#pragma unroll
  for (int rr = 0; rr < 8; ++rr) {
    int r = r0 + rr;
    loadrow(r + 2, Ae[3], Ao[3], Be[3], Bo[3]);
    float4 ee = f4z(), eo = f4z(), oe = f4z(), oo = f4z();
#pragma unroll
    for (int dm = 0; dm < 4; ++dm) {
      float gye = c_g0[2 * dm + 1], hye = c_g1[2 * dm + 1];
      float gyo = c_g0[2 * dm],     hyo = c_g1[2 * dm];
      ee = f4fma(ee, gye, Ae[dm]); ee = f4fma(ee, hye, Be[dm]);
      eo = f4fma(eo, gye, Ao[dm]); eo = f4fma(eo, hye, Bo[dm]);
      oe = f4fma(oe, gyo, Ae[dm]); oe = f4fma(oe, hyo, Be[dm]);
      oo = f4fma(oo, gyo, Ao[dm]); oo = f4fma(oo, hyo, Bo[dm]);
    }
    int y = 2 * r, xx = 2 * q;
    float* ob = res + (((size_t)(b * 64 + y)) * 64 + xx) * 64 + (c4 << 2);
    *(float4*)(ob)                = ee;
    *(float4*)(ob + 64)           = eo;
    *(float4*)(ob + 4096)         = oe;
    *(float4*)(ob + 4096 + 64)    = oo;
#pragma unroll
    for (int k = 0; k < 3; ++k) {
      Ae[k] = Ae[k + 1]; Ao[k] = Ao[k + 1]; Be[k] = Be[k + 1]; Bo[k] = Bo[k + 1];
    }
  }
}

// ---- Final synthesis: res (32,64,64,64) -> out (32,128,128,64), g0 x g0 ----
__global__ __launch_bounds__(256) void k_final(const float* __restrict__ res,
                                               float* __restrict__ out) {
  int t = threadIdx.x;
  int c4 = t & 15;
  int ql = t >> 4;
  int bid = blockIdx.x;             // b*16 + rc*4 + qb
  int qb = bid & 3;
  int rc = (bid >> 2) & 3;
  int b  = bid >> 4;
  int q  = qb * 16 + ql;
  int r0 = rc * 16;

  float4 R0[4], R1[4];
  auto loadrow = [&](int m, float4& row0, float4& row1) {
    row0 = f4z(); row1 = f4z();
    if ((unsigned)m >= 64u) return;
    const float* base = res + (((size_t)(b * 64 + m)) * 64) * 64 + (c4 << 2);
    float4 v[4];
#pragma unroll
    for (int dn = -1; dn <= 2; ++dn) {
      int n = q + dn;
      int nc = min(max(n, 0), 63);
      v[dn + 1] = *(const float4*)(base + (nc << 6));
    }
#pragma unroll
    for (int dn = -1; dn <= 2; ++dn) {
      int n = q + dn;
      bool ok = (unsigned)n < 64u;
      float we = ok ? c_g0[2 * dn + 3] : 0.f;
      float wo = ok ? c_g0[2 * dn + 2] : 0.f;
      row0 = f4fma(row0, we, v[dn + 1]);
      row1 = f4fma(row1, wo, v[dn + 1]);
    }
  };

#pragma unroll
  for (int k = 0; k < 3; ++k) loadrow(r0 - 1 + k, R0[k], R1[k]);
#pragma unroll
  for (int rr = 0; rr < 16; ++rr) {
    int r = r0 + rr;
    loadrow(r + 2, R0[3], R1[3]);
    float4 aee = f4z(), aeo = f4z(), aoe = f4z(), aoo = f4z();
#pragma unroll
    for (int dm = 0; dm < 4; ++dm) {
      float gye = c_g0[2 * dm + 1];
      float gyo = c_g0[2 * dm];
      aee = f4fma(aee, gye, R0[dm]);
      aeo = f4fma(aeo, gye, R1[dm]);
      aoe = f4fma(aoe, gyo, R0[dm]);
      aoo = f4fma(aoo, gyo, R1[dm]);
    }
    int y = 2 * r, xx = 2 * q;
    float* ob = out + (((size_t)(b * 128 + y)) * 128 + xx) * 64 + (c4 << 2);
    *(float4*)(ob)                 = aee;
    *(float4*)(ob + 64)            = aeo;
    *(float4*)(ob + 8192)          = aoe;
    *(float4*)(ob + 8192 + 64)     = aoo;
#pragma unroll
    for (int k = 0; k < 3; ++k) { R0[k] = R0[k + 1]; R1[k] = R1[k + 1]; }
  }
}

extern "C" void kernel_launch(void* const* d_in, const int* in_sizes, int n_in,
                              void* d_out, int out_size, void* d_ws, size_t ws_size,
                              hipStream_t stream) {
  (void)in_sizes; (void)n_in; (void)out_size;
  const float* x  = (const float*)d_in[0];
  const float* w1 = (const float*)d_in[1];
  const float* w2 = (const float*)d_in[2];
  const float* w3 = (const float*)d_in[3];
  const float* w4 = (const float*)d_in[4];
  float* out = (float*)d_out;
  float* ws  = (float*)d_ws;

  // Workspace layout (floats):
  //   [0,        8388608)  ll1, later reused as res
  //   [8388608, 16777216)  subs (4 x 2097152)
  //   [16777216,25165824)  eout (4 x 2097152)
  //   [25165824,41943040)  wt (4 x 4194304), optional
  float* ll1  = ws;
  float* subs = ws + 8388608;
  float* eout = ws + 16777216;
  float* res  = ws;  // reuse ll1 (dead after k_dwt2)
  float* wt   = ws + 25165824;
  int use_wt = (ws_size >= (size_t)41943040 * 4) ? 1 : 0;

  // DIAGNOSTIC: run the full idempotent chain twice.
  // dur_us(this) - dur_us(prev) == exact sum of all kernel times.
  for (int pass = 0; pass < 2; ++pass) {
    k_dwt1<<<1024, 256, 0, stream>>>(x, ll1);
    if (use_wt) k_transpose<<<dim3(32, 128, 4), 256, 0, stream>>>(w1, w2, w3, w4, wt);
    k_dwt2<<<512, 256, 0, stream>>>(ll1, subs);
    k_einsum<<<dim3(1024, 4), 256, 0, stream>>>(subs, w1, w2, w3, w4, wt, eout, use_wt);
    k_invres<<<256, 256, 0, stream>>>(eout, res);
    k_final<<<512, 256, 0, stream>>>(res, out);
  }
}

// Round 6
// 372.829 us; speedup vs baseline: 1.5010x; 1.5010x over previous
//
#include <hip/hip_runtime.h>

// WaveletConv2D: 2-level DWT (8-tap), per-position 64x64 channel mix on the
// 4 level-2 subbands, then 2-level inverse DWT. All fp32.
// R8: R7 diagnostic showed chain = 174us, fixed harness overhead = 212us.
// Two structural cuts: (1) transpose merged into dwt1 dispatch (independent
// work, runs concurrently, hides under dwt1 latency slack); (2) invres+final
// fused: res rows computed into an LDS ring (3 pairs x 20 cols x 16 c4),
// synthesis filter applied in-block -> 67MB res round-trip + 1 launch gone.

__constant__ float c_h0[8] = {0.0322231f, -0.01260397f, -0.09921954f, 0.2978578f,
                              0.80373875f, 0.49761867f, -0.02963553f, -0.07576571f};
__constant__ float c_h1[8] = {0.07576571f, -0.02963553f, -0.49761867f, 0.80373875f,
                              -0.2978578f, -0.09921954f, 0.01260397f, 0.0322231f};
// g0 = reverse(h0), g1 = reverse(h1)
__constant__ float c_g0[8] = {-0.07576571f, -0.02963553f, 0.49761867f, 0.80373875f,
                              0.2978578f, -0.09921954f, -0.01260397f, 0.0322231f};
__constant__ float c_g1[8] = {0.0322231f, 0.01260397f, -0.09921954f, -0.2978578f,
                              0.80373875f, -0.49761867f, -0.02963553f, 0.07576571f};

__device__ __forceinline__ float4 f4z() { return make_float4(0.f, 0.f, 0.f, 0.f); }
__device__ __forceinline__ float4 f4fma(float4 a, float w, float4 v) {
  a.x = fmaf(w, v.x, a.x); a.y = fmaf(w, v.y, a.y);
  a.z = fmaf(w, v.z, a.z); a.w = fmaf(w, v.w, a.w);
  return a;
}

// ---- Stage 1 + weight transpose in one dispatch ----
// Blocks [0,1024): x (32,128,128,64) -> ll1 (32,64,64,64), h0 x h0, stride 2.
// Blocks [1024, 1024+16384): W[i,o,hw] -> Wt[hw][io], 32x32 tiles.
__global__ __launch_bounds__(256) void k_dwt1t(const float* __restrict__ x,
                                               float* __restrict__ ll1,
                                               const float* __restrict__ w1,
                                               const float* __restrict__ w2,
                                               const float* __restrict__ w3,
                                               const float* __restrict__ w4,
                                               float* __restrict__ wt) {
  __shared__ float4 sRow[2][40 * 17];   // 21760 B; transpose path reuses it
  int t = threadIdx.x;
  int bid = blockIdx.x;

  if (bid >= 1024) {
    // ---- transpose path ----
    int bid2 = bid - 1024;
    int s   = bid2 >> 12;               // 0..3
    int rem = bid2 & 4095;
    int hw0 = (rem & 31) * 32;
    int io0 = (rem >> 5) * 32;
    const float* w = (s == 0) ? w1 : (s == 1) ? w2 : (s == 2) ? w3 : w4;
    float* tile = (float*)sRow;         // [32][33]
    int tx = t & 31;
    int ty = t >> 5;                    // 0..7
#pragma unroll
    for (int k = 0; k < 4; ++k) {
      int r = ty + k * 8;
      tile[r * 33 + tx] = w[(io0 + r) * 1024 + hw0 + tx];
    }
    __syncthreads();
    float* o = wt + (size_t)s * 4194304;
#pragma unroll
    for (int k = 0; k < 4; ++k) {
      int r = ty + k * 8;
      o[(hw0 + r) * 4096 + io0 + tx] = tile[tx * 33 + r];
    }
    return;
  }

  // ---- dwt1 path ----
  int c4 = t & 15;
  int owl = t >> 4;                 // 0..15
  int owb = bid & 3;
  int ohc = (bid >> 2) & 7;
  int b   = bid >> 5;
  int ow0 = owb * 16;
  int ow  = ow0 + owl;
  int oh0 = ohc * 8;
  int iw_start = 2 * ow0 - 3;       // global iw of LDS slot 0
  const float* xb = x + ((size_t)b << 20);

  auto stage2 = [&](int ih0) {
#pragma unroll
    for (int base = 0; base < 80; base += 16) {
      int item = base + owl;        // 0..79
      int rw   = item >= 40 ? 1 : 0;
      int iw_s = item - rw * 40;
      int ihc  = min(max(ih0 + rw, 0), 127);
      int iwc  = min(max(iw_start + iw_s, 0), 127);
      sRow[rw][iw_s * 17 + c4] =
          *(const float4*)(xb + (size_t)ihc * 8192 + (iwc << 6) + (c4 << 2));
    }
  };

  auto hrowL = [&](int rw, int ih) -> float4 {
    float4 r = f4z();
    if ((unsigned)ih >= 128u) return r;
#pragma unroll
    for (int j = 0; j < 8; ++j) {
      int iw  = 2 * ow - 3 + j;
      int iwc = min(max(iw, 0), 127);
      int iw_s = iwc - iw_start;    // in [0,39]
      float w = ((unsigned)iw < 128u) ? c_h0[j] : 0.f;
      r = f4fma(r, w, sRow[rw][iw_s * 17 + c4]);
    }
    return r;
  };

  float4 ring[8];
  int ihb = 2 * oh0 - 3;
#pragma unroll
  for (int pk = 0; pk < 3; ++pk) {
    stage2(ihb + 2 * pk);
    __syncthreads();
    ring[2 * pk]     = hrowL(0, ihb + 2 * pk);
    ring[2 * pk + 1] = hrowL(1, ihb + 2 * pk + 1);
    __syncthreads();
  }
  float* outp = ll1 + ((((size_t)b * 64 + oh0) * 64 + ow) << 6) + (c4 << 2);
#pragma unroll
  for (int oo = 0; oo < 8; ++oo) {
    stage2(ihb + 6);
    __syncthreads();
    ring[6] = hrowL(0, ihb + 6);
    ring[7] = hrowL(1, ihb + 7);
    float4 a = f4z();
#pragma unroll
    for (int i = 0; i < 8; ++i) a = f4fma(a, c_h0[i], ring[i]);
    *(float4*)(outp + oo * 4096) = a;
    __syncthreads();
#pragma unroll
    for (int k = 0; k < 6; ++k) ring[k] = ring[k + 2];
    ihb += 2;
  }
}

// ---- Stage 2: ll1 (32,64,64,64) -> 4 subbands (32,32,32,64) ----
__global__ __launch_bounds__(256) void k_dwt2(const float* __restrict__ ll1,
                                              float* __restrict__ subs) {
  __shared__ float4 sRow[2][40 * 17];
  int t = threadIdx.x;
  int c4 = t & 15;
  int owl = t >> 4;
  int bid = blockIdx.x;             // b*16 + ohc*2 + owb
  int owb = bid & 1;
  int ohc = (bid >> 1) & 7;
  int b   = bid >> 4;
  int ow0 = owb * 16;
  int ow  = ow0 + owl;
  int oh0 = ohc * 4;
  int iw_start = 2 * ow0 - 3;
  const float* lb = ll1 + ((size_t)b << 18);

  auto stage2 = [&](int ih0) {
#pragma unroll
    for (int base = 0; base < 80; base += 16) {
      int item = base + owl;
      int rw   = item >= 40 ? 1 : 0;
      int iw_s = item - rw * 40;
      int ihc  = min(max(ih0 + rw, 0), 63);
      int iwc  = min(max(iw_start + iw_s, 0), 63);
      sRow[rw][iw_s * 17 + c4] =
          *(const float4*)(lb + (size_t)ihc * 4096 + (iwc << 6) + (c4 << 2));
    }
  };

  auto hrow2L = [&](int rw, int ih, float4& rl, float4& rh) {
    rl = f4z(); rh = f4z();
    if ((unsigned)ih >= 64u) return;
#pragma unroll
    for (int j = 0; j < 8; ++j) {
      int iw  = 2 * ow - 3 + j;
      int iwc = min(max(iw, 0), 63);
      int iw_s = iwc - iw_start;
      bool ok = (unsigned)iw < 64u;
      float wl = ok ? c_h0[j] : 0.f;
      float wh = ok ? c_h1[j] : 0.f;
      float4 v = sRow[rw][iw_s * 17 + c4];
      rl = f4fma(rl, wl, v);
      rh = f4fma(rh, wh, v);
    }
  };

  float4 Rl[8], Rh[8];
  int ihb = 2 * oh0 - 3;
#pragma unroll
  for (int pk = 0; pk < 3; ++pk) {
    stage2(ihb + 2 * pk);
    __syncthreads();
    hrow2L(0, ihb + 2 * pk,     Rl[2 * pk],     Rh[2 * pk]);
    hrow2L(1, ihb + 2 * pk + 1, Rl[2 * pk + 1], Rh[2 * pk + 1]);
    __syncthreads();
  }
  float* outp = subs + ((((size_t)b * 32 + oh0) * 32 + ow) << 6) + (c4 << 2);
#pragma unroll
  for (int oo = 0; oo < 4; ++oo) {
    stage2(ihb + 6);
    __syncthreads();
    hrow2L(0, ihb + 6, Rl[6], Rh[6]);
    hrow2L(1, ihb + 7, Rl[7], Rh[7]);
    float4 a_ll = f4z(), a_lh = f4z(), a_hl = f4z(), a_hh = f4z();
#pragma unroll
    for (int i = 0; i < 8; ++i) {
      a_ll = f4fma(a_ll, c_h0[i], Rl[i]);
      a_lh = f4fma(a_lh, c_h0[i], Rh[i]);
      a_hl = f4fma(a_hl, c_h1[i], Rl[i]);
      a_hh = f4fma(a_hh, c_h1[i], Rh[i]);
    }
    float* o = outp + oo * 2048;
    *(float4*)(o)           = a_ll;
    *(float4*)(o + 2097152) = a_lh;
    *(float4*)(o + 4194304) = a_hl;
    *(float4*)(o + 6291456) = a_hh;
    __syncthreads();
#pragma unroll
    for (int k = 0; k < 6; ++k) { Rl[k] = Rl[k + 2]; Rh[k] = Rh[k + 2]; }
    ihb += 2;
  }
}

// ---- Einsum: out[b,p,o] = sum_i A[b,p,i] * W[i,o,p], per spatial position p ----
__global__ __launch_bounds__(256) void k_einsum(const float* __restrict__ subs,
                                               const float* __restrict__ w1,
                                               const float* __restrict__ w2,
                                               const float* __restrict__ w3,
                                               const float* __restrict__ w4,
                                               const float* __restrict__ wt,
                                               float* __restrict__ eout,
                                               int use_wt) {
  __shared__ float sW[4096];  // [i][o]
  __shared__ float sA[2048];  // [b][i]
  int p = blockIdx.x;   // 0..1023 = h*32+w
  int s = blockIdx.y;   // subband
  int t = threadIdx.x;
  const float* A = subs + (size_t)s * 2097152;
  if (use_wt) {
    const float* Wp = wt + (size_t)s * 4194304 + (size_t)p * 4096;
#pragma unroll
    for (int k = 0; k < 16; ++k) sW[t + 256 * k] = Wp[t + 256 * k];
  } else {
    const float* Ws = (s == 0) ? w1 : (s == 1) ? w2 : (s == 2) ? w3 : w4;
#pragma unroll
    for (int k = 0; k < 16; ++k) {
      int e = t + 256 * k;
      sW[e] = Ws[e * 1024 + p];
    }
  }
#pragma unroll
  for (int k = 0; k < 8; ++k) {
    int e = t + 256 * k;                       // e = b*64 + i
    sA[e] = A[(e >> 6) * 65536 + (p << 6) + (e & 63)];
  }
  __syncthreads();
  int o  = t & 63;
  int bg = t >> 6;  // 0..3, handles b = bg*8 .. bg*8+7
  float acc[8] = {0.f, 0.f, 0.f, 0.f, 0.f, 0.f, 0.f, 0.f};
  for (int i = 0; i < 64; ++i) {
    float wv = sW[(i << 6) + o];
#pragma unroll
    for (int k = 0; k < 8; ++k) acc[k] += sA[((bg * 8 + k) << 6) + i] * wv;
  }
  float* Oo = eout + (size_t)s * 2097152 + (p << 6) + o;
#pragma unroll
  for (int k = 0; k < 8; ++k) Oo[(bg * 8 + k) * 65536] = acc[k];
}

// ---- Fused inverse: 4 subbands eout (32,32,32,64) -> out (32,128,128,64) ----
// Block: (b, ytile of 32 out rows, xtile of 32 out cols). res rows are
// computed into an LDS ring of 3 row-pairs x 20 cols (halo incl.) x 16 c4,
// then the g0 x g0 synthesis filter reads the ring. Edge semantics identical
// to the original k_invres (row-zero outside [0,32), col-weight-zero) and
// k_final (row-pairs outside [0,32) are zero; col-weight-zero outside [0,64)).
__global__ __launch_bounds__(256) void k_invfinal(const float* __restrict__ eout,
                                                  float* __restrict__ out) {
  __shared__ float4 sRes[3][2][20][16];   // 30720 B
  int t = threadIdx.x;
  int c4 = t & 15;
  int ql = t >> 4;                  // 0..15
  int bid = blockIdx.x;             // b*16 + yt*4 + xt
  int xt = bid & 3;
  int yt = (bid >> 2) & 3;
  int b  = bid >> 4;
  int q0 = xt * 16;                 // final-q base (out cols 2q0..2q0+31)
  int qi0 = (q0 >> 1) - 1;          // invres-q base (10 slots)
  int qi = qi0 + ql;                // valid work for ql < 10
  int r0p = yt * 8;                 // first emitted res-pair index

  // invres eout-row filter (identical math to original k_invres::loadrow)
  auto loadrowI = [&](int m, float4& ae, float4& ao, float4& be, float4& bo) {
    ae = f4z(); ao = f4z(); be = f4z(); bo = f4z();
    if ((unsigned)m >= 32u) return;
    const float* base = eout + ((((size_t)b * 32 + m) * 32) << 6) + (c4 << 2);
    float4 vf[4], vl[4], vh[4], vv[4];
#pragma unroll
    for (int dn = -1; dn <= 2; ++dn) {
      int n = qi + dn;
      int nc = min(max(n, 0), 31);
      const float* p = base + (nc << 6);
      vf[dn + 1] = *(const float4*)(p);
      vl[dn + 1] = *(const float4*)(p + 2097152);
      vh[dn + 1] = *(const float4*)(p + 4194304);
      vv[dn + 1] = *(const float4*)(p + 6291456);
    }
#pragma unroll
    for (int dn = -1; dn <= 2; ++dn) {
      int n = qi + dn;
      bool ok = (unsigned)n < 32u;
      float g0e = ok ? c_g0[2 * dn + 3] : 0.f, g1e = ok ? c_g1[2 * dn + 3] : 0.f;
      float g0o = ok ? c_g0[2 * dn + 2] : 0.f, g1o = ok ? c_g1[2 * dn + 2] : 0.f;
      ae = f4fma(ae, g0e, vf[dn + 1]); ae = f4fma(ae, g1e, vl[dn + 1]);
      ao = f4fma(ao, g0o, vf[dn + 1]); ao = f4fma(ao, g1o, vl[dn + 1]);
      be = f4fma(be, g0e, vh[dn + 1]); be = f4fma(be, g1e, vv[dn + 1]);
      bo = f4fma(bo, g0o, vh[dn + 1]); bo = f4fma(bo, g1o, vv[dn + 1]);
    }
  };

  float4 Ae[4], Ao[4], Be[4], Bo[4];
  int prs = r0p - 1;                // pair cursor

  // compute res pair prs from ring (rows prs-1..prs+2) and store to LDS
  auto steppair = [&]() {
    loadrowI(prs + 2, Ae[3], Ao[3], Be[3], Bo[3]);
    float4 ee = f4z(), eo = f4z(), oe = f4z(), oo = f4z();
    if ((unsigned)prs < 32u) {
#pragma unroll
      for (int dm = 0; dm < 4; ++dm) {
        float gye = c_g0[2 * dm + 1], hye = c_g1[2 * dm + 1];
        float gyo = c_g0[2 * dm],     hyo = c_g1[2 * dm];
        ee = f4fma(ee, gye, Ae[dm]); ee = f4fma(ee, hye, Be[dm]);
        eo = f4fma(eo, gye, Ao[dm]); eo = f4fma(eo, hye, Bo[dm]);
        oe = f4fma(oe, gyo, Ae[dm]); oe = f4fma(oe, hyo, Be[dm]);
        oo = f4fma(oo, gyo, Ao[dm]); oo = f4fma(oo, hyo, Bo[dm]);
      }
    }
    int slot = ((prs % 3) + 3) % 3;
    sRes[slot][0][2 * ql][c4]     = ee;
    sRes[slot][0][2 * ql + 1][c4] = eo;
    sRes[slot][1][2 * ql][c4]     = oe;
    sRes[slot][1][2 * ql + 1][c4] = oo;
#pragma unroll
    for (int k = 0; k < 3; ++k) {
      Ae[k] = Ae[k + 1]; Ao[k] = Ao[k + 1]; Be[k] = Be[k + 1]; Bo[k] = Bo[k + 1];
    }
  };

  if (ql < 10) {
    loadrowI(prs - 1, Ae[0], Ao[0], Be[0], Bo[0]);
    loadrowI(prs,     Ae[1], Ao[1], Be[1], Bo[1]);
    loadrowI(prs + 1, Ae[2], Ao[2], Be[2], Bo[2]);
  }
  // prologue pairs r0p-1, r0p
#pragma unroll
  for (int pk = 0; pk < 2; ++pk) {
    if (ql < 10) steppair();
    ++prs;
  }
  int q = q0 + ql;
#pragma unroll
  for (int it = 0; it < 8; ++it) {
    if (ql < 10) steppair();       // computes pair prs
    __syncthreads();
    // emit out pairs r = 2*(prs-1), 2*(prs-1)+1 (4 out rows)
    float4 H0[5], H1[5];
#pragma unroll
    for (int mi = 0; mi < 5; ++mi) {
      int m = 2 * (prs - 1) - 1 + mi;  // res row
      int pm = m >> 1;
      int ey = m & 1;
      int slot = ((pm % 3) + 3) % 3;
      float4 h0v = f4z(), h1v = f4z();
#pragma unroll
      for (int dn = -1; dn <= 2; ++dn) {
        int n = q + dn;
        bool ok = (unsigned)n < 64u;
        float we = ok ? c_g0[2 * dn + 3] : 0.f;
        float wo = ok ? c_g0[2 * dn + 2] : 0.f;
        float4 v = sRes[slot][ey][ql + 2 + dn][c4];
        h0v = f4fma(h0v, we, v);
        h1v = f4fma(h1v, wo, v);
      }
      H0[mi] = h0v; H1[mi] = h1v;
    }
#pragma unroll
    for (int rr2 = 0; rr2 < 2; ++rr2) {
      int r = 2 * (prs - 1) + rr2;
      float4 aee = f4z(), aeo = f4z(), aoe = f4z(), aoo = f4z();
#pragma unroll
      for (int dm = 0; dm < 4; ++dm) {
        float gye = c_g0[2 * dm + 1];
        float gyo = c_g0[2 * dm];
        aee = f4fma(aee, gye, H0[rr2 + dm]);
        aeo = f4fma(aeo, gye, H1[rr2 + dm]);
        aoe = f4fma(aoe, gyo, H0[rr2 + dm]);
        aoo = f4fma(aoo, gyo, H1[rr2 + dm]);
      }
      int y = 2 * r, xx = 2 * q;
      float* ob = out + (((size_t)(b * 128 + y)) * 128 + xx) * 64 + (c4 << 2);
      *(float4*)(ob)              = aee;
      *(float4*)(ob + 64)         = aeo;
      *(float4*)(ob + 8192)       = aoe;
      *(float4*)(ob + 8192 + 64)  = aoo;
    }
    __syncthreads();
    ++prs;
  }
}

extern "C" void kernel_launch(void* const* d_in, const int* in_sizes, int n_in,
                              void* d_out, int out_size, void* d_ws, size_t ws_size,
                              hipStream_t stream) {
  (void)in_sizes; (void)n_in; (void)out_size;
  const float* x  = (const float*)d_in[0];
  const float* w1 = (const float*)d_in[1];
  const float* w2 = (const float*)d_in[2];
  const float* w3 = (const float*)d_in[3];
  const float* w4 = (const float*)d_in[4];
  float* out = (float*)d_out;
  float* ws  = (float*)d_ws;

  // Workspace layout (floats):
  //   [0,        8388608)  ll1
  //   [8388608, 16777216)  subs (4 x 2097152)
  //   [16777216,25165824)  eout (4 x 2097152)
  //   [25165824,41943040)  wt (4 x 4194304), optional
  float* ll1  = ws;
  float* subs = ws + 8388608;
  float* eout = ws + 16777216;
  float* wt   = ws + 25165824;
  int use_wt = (ws_size >= (size_t)41943040 * 4) ? 1 : 0;

  int g1 = use_wt ? (1024 + 16384) : 1024;
  k_dwt1t<<<g1, 256, 0, stream>>>(x, ll1, w1, w2, w3, w4, wt);
  k_dwt2<<<512, 256, 0, stream>>>(ll1, subs);
  k_einsum<<<dim3(1024, 4), 256, 0, stream>>>(subs, w1, w2, w3, w4, wt, eout, use_wt);
  k_invfinal<<<512, 256, 0, stream>>>(eout, out);
}

// Round 8
// 364.928 us; speedup vs baseline: 1.5335x; 1.0216x over previous
//
#include <hip/hip_runtime.h>

// WaveletConv2D: 2-level DWT (8-tap), per-position 64x64 channel mix on the
// 4 level-2 subbands, then 2-level inverse DWT. All fp32.
// R9 (resubmit; previous run died to container infra, not the kernel):
// k_dwt1t measured 100us (62% of chain) with ALL pipes idle (HBM 30%,
// VALU 9%, occ 30%) -> latency/phase-bound. (1) transpose: 64x64 tiles,
// float4 both global sides (4x fewer VMEM ops + blocks; was scalar 128B
// bursts). (2) dwt1: march 16 rows, 4-row stage phases -> barriers/output
// 2.75->1.25, loads-in-flight/thread 5->10.

__constant__ float c_h0[8] = {0.0322231f, -0.01260397f, -0.09921954f, 0.2978578f,
                              0.80373875f, 0.49761867f, -0.02963553f, -0.07576571f};
__constant__ float c_h1[8] = {0.07576571f, -0.02963553f, -0.49761867f, 0.80373875f,
                              -0.2978578f, -0.09921954f, 0.01260397f, 0.0322231f};
// g0 = reverse(h0), g1 = reverse(h1)
__constant__ float c_g0[8] = {-0.07576571f, -0.02963553f, 0.49761867f, 0.80373875f,
                              0.2978578f, -0.09921954f, -0.01260397f, 0.0322231f};
__constant__ float c_g1[8] = {0.0322231f, 0.01260397f, -0.09921954f, -0.2978578f,
                              0.80373875f, -0.49761867f, -0.02963553f, 0.07576571f};

__device__ __forceinline__ float4 f4z() { return make_float4(0.f, 0.f, 0.f, 0.f); }
__device__ __forceinline__ float4 f4fma(float4 a, float w, float4 v) {
  a.x = fmaf(w, v.x, a.x); a.y = fmaf(w, v.y, a.y);
  a.z = fmaf(w, v.z, a.z); a.w = fmaf(w, v.w, a.w);
  return a;
}

// ---- Stage 1 + weight transpose in one dispatch ----
// Blocks [0,512): x (32,128,128,64) -> ll1 (32,64,64,64), h0 x h0, stride 2.
//   Block = (b, ohc of 16 oh, owb of 16 ow); 4-row LDS stage phases.
// Blocks [512, 512+4096): W[i,o,hw] -> Wt[hw][io], 64x64 float4 tiles.
__global__ __launch_bounds__(256) void k_dwt1t(const float* __restrict__ x,
                                               float* __restrict__ ll1,
                                               const float* __restrict__ w1,
                                               const float* __restrict__ w2,
                                               const float* __restrict__ w3,
                                               const float* __restrict__ w4,
                                               float* __restrict__ wt) {
  __shared__ float4 sRow[4][40 * 17];   // 43520 B; transpose path reuses it
  int t = threadIdx.x;
  int bid = blockIdx.x;

  if (bid >= 512) {
    // ---- transpose path: 64x64 tile, float4 both ways ----
    int bid2 = bid - 512;
    int s   = bid2 >> 10;               // 0..3
    int rem = bid2 & 1023;
    int hw0 = (rem & 15) << 6;          // 16 hw-tiles
    int io0 = (rem >> 4) << 6;          // 64 io-tiles
    const float* w = (s == 0) ? w1 : (s == 1) ? w2 : (s == 2) ? w3 : w4;
    float* tile = (float*)sRow;         // [64][65] floats = 16640 B
    int c = t & 15;                     // hw float4 lane
    int r = t >> 4;                     // 0..15
#pragma unroll
    for (int k = 0; k < 4; ++k) {
      int io = r + 16 * k;              // io_local 0..63
      float4 v = *(const float4*)(w + (size_t)(io0 + io) * 1024 + hw0 + c * 4);
      tile[io * 65 + c * 4 + 0] = v.x;
      tile[io * 65 + c * 4 + 1] = v.y;
      tile[io * 65 + c * 4 + 2] = v.z;
      tile[io * 65 + c * 4 + 3] = v.w;
    }
    __syncthreads();
    float* o = wt + (size_t)s * 4194304;
#pragma unroll
    for (int k = 0; k < 4; ++k) {
      int hr = r + 16 * k;              // hw_local 0..63
      float4 v;
      v.x = tile[(c * 4 + 0) * 65 + hr];
      v.y = tile[(c * 4 + 1) * 65 + hr];
      v.z = tile[(c * 4 + 2) * 65 + hr];
      v.w = tile[(c * 4 + 3) * 65 + hr];
      *(float4*)(o + (size_t)(hw0 + hr) * 4096 + io0 + c * 4) = v;
    }
    return;
  }

  // ---- dwt1 path ----
  int c4 = t & 15;
  int owl = t >> 4;                 // 0..15
  int owb = bid & 3;
  int ohc = (bid >> 2) & 3;
  int b   = bid >> 4;               // 0..31
  int ow0 = owb * 16;
  int ow  = ow0 + owl;
  int oh0 = ohc * 16;
  int iw_start = 2 * ow0 - 3;       // global iw of LDS slot 0
  const float* xb = x + ((size_t)b << 20);

  // stage nrows rows starting at ih0 into sRow[0..nrows-1]
  auto stageN = [&](int ih0, int nrows) {
    int items = nrows * 40;
    for (int base = 0; base < items; base += 16) {
      int item = base + owl;
      int rw   = item / 40;
      int iw_s = item - rw * 40;
      int ihc  = min(max(ih0 + rw, 0), 127);
      int iwc  = min(max(iw_start + iw_s, 0), 127);
      sRow[rw][iw_s * 17 + c4] =
          *(const float4*)(xb + (size_t)ihc * 8192 + (iwc << 6) + (c4 << 2));
    }
  };

  // horizontal filter of staged row slot rw (global row index ih)
  auto hrowL = [&](int rw, int ih) -> float4 {
    float4 r = f4z();
    if ((unsigned)ih >= 128u) return r;
#pragma unroll
    for (int j = 0; j < 8; ++j) {
      int iw  = 2 * ow - 3 + j;
      int iwc = min(max(iw, 0), 127);
      int iw_s = iwc - iw_start;    // in [0,39]
      float w = ((unsigned)iw < 128u) ? c_h0[j] : 0.f;
      r = f4fma(r, w, sRow[rw][iw_s * 17 + c4]);
    }
    return r;
  };

  float4 ring[10];
  int ihb = 2 * oh0 - 3;
  // prologue: rows ihb..ihb+7 -> ring[0..7]
  stageN(ihb, 4);
  __syncthreads();
#pragma unroll
  for (int k = 0; k < 4; ++k) ring[k] = hrowL(k, ihb + k);
  __syncthreads();
  stageN(ihb + 4, 4);
  __syncthreads();
#pragma unroll
  for (int k = 0; k < 4; ++k) ring[4 + k] = hrowL(k, ihb + 4 + k);
  __syncthreads();

  float* outp = ll1 + ((((size_t)b * 64 + oh0) * 64 + ow) << 6) + (c4 << 2);
#pragma unroll
  for (int p = 0; p < 8; ++p) {
    // stage rows for ring[8..9] (phase 0: 2 rows) or ring[6..9] (else: 4 rows)
    int nfill = (p == 0) ? 2 : 4;
    int fill0 = 10 - nfill;
    stageN(ihb + 4 * p + fill0, nfill);
    __syncthreads();
#pragma unroll
    for (int k = 0; k < 4; ++k) {
      if (k < nfill) ring[fill0 + k] = hrowL(k, ihb + 4 * p + fill0 + k);
    }
    // outputs oh0+2p (ring[0..7]) and oh0+2p+1 (ring[2..9])
    float4 a0 = f4z(), a1 = f4z();
#pragma unroll
    for (int i = 0; i < 8; ++i) {
      a0 = f4fma(a0, c_h0[i], ring[i]);
      a1 = f4fma(a1, c_h0[i], ring[i + 2]);
    }
    *(float4*)(outp + (2 * p) * 4096)     = a0;
    *(float4*)(outp + (2 * p + 1) * 4096) = a1;
    __syncthreads();
#pragma unroll
    for (int k = 0; k < 6; ++k) ring[k] = ring[k + 4];
  }
}

// ---- Stage 2: ll1 (32,64,64,64) -> 4 subbands (32,32,32,64) ----
__global__ __launch_bounds__(256) void k_dwt2(const float* __restrict__ ll1,
                                              float* __restrict__ subs) {
  __shared__ float4 sRow[2][40 * 17];
  int t = threadIdx.x;
  int c4 = t & 15;
  int owl = t >> 4;
  int bid = blockIdx.x;             // b*16 + ohc*2 + owb
  int owb = bid & 1;
  int ohc = (bid >> 1) & 7;
  int b   = bid >> 4;
  int ow0 = owb * 16;
  int ow  = ow0 + owl;
  int oh0 = ohc * 4;
  int iw_start = 2 * ow0 - 3;
  const float* lb = ll1 + ((size_t)b << 18);

  auto stage2 = [&](int ih0) {
#pragma unroll
    for (int base = 0; base < 80; base += 16) {
      int item = base + owl;
      int rw   = item >= 40 ? 1 : 0;
      int iw_s = item - rw * 40;
      int ihc  = min(max(ih0 + rw, 0), 63);
      int iwc  = min(max(iw_start + iw_s, 0), 63);
      sRow[rw][iw_s * 17 + c4] =
          *(const float4*)(lb + (size_t)ihc * 4096 + (iwc << 6) + (c4 << 2));
    }
  };

  auto hrow2L = [&](int rw, int ih, float4& rl, float4& rh) {
    rl = f4z(); rh = f4z();
    if ((unsigned)ih >= 64u) return;
#pragma unroll
    for (int j = 0; j < 8; ++j) {
      int iw  = 2 * ow - 3 + j;
      int iwc = min(max(iw, 0), 63);
      int iw_s = iwc - iw_start;
      bool ok = (unsigned)iw < 64u;
      float wl = ok ? c_h0[j] : 0.f;
      float wh = ok ? c_h1[j] : 0.f;
      float4 v = sRow[rw][iw_s * 17 + c4];
      rl = f4fma(rl, wl, v);
      rh = f4fma(rh, wh, v);
    }
  };

  float4 Rl[8], Rh[8];
  int ihb = 2 * oh0 - 3;
#pragma unroll
  for (int pk = 0; pk < 3; ++pk) {
    stage2(ihb + 2 * pk);
    __syncthreads();
    hrow2L(0, ihb + 2 * pk,     Rl[2 * pk],     Rh[2 * pk]);
    hrow2L(1, ihb + 2 * pk + 1, Rl[2 * pk + 1], Rh[2 * pk + 1]);
    __syncthreads();
  }
  float* outp = subs + ((((size_t)b * 32 + oh0) * 32 + ow) << 6) + (c4 << 2);
#pragma unroll
  for (int oo = 0; oo < 4; ++oo) {
    stage2(ihb + 6);
    __syncthreads();
    hrow2L(0, ihb + 6, Rl[6], Rh[6]);
    hrow2L(1, ihb + 7, Rl[7], Rh[7]);
    float4 a_ll = f4z(), a_lh = f4z(), a_hl = f4z(), a_hh = f4z();
#pragma unroll
    for (int i = 0; i < 8; ++i) {
      a_ll = f4fma(a_ll, c_h0[i], Rl[i]);
      a_lh = f4fma(a_lh, c_h0[i], Rh[i]);
      a_hl = f4fma(a_hl, c_h1[i], Rl[i]);
      a_hh = f4fma(a_hh, c_h1[i], Rh[i]);
    }
    float* o = outp + oo * 2048;
    *(float4*)(o)           = a_ll;
    *(float4*)(o + 2097152) = a_lh;
    *(float4*)(o + 4194304) = a_hl;
    *(float4*)(o + 6291456) = a_hh;
    __syncthreads();
#pragma unroll
    for (int k = 0; k < 6; ++k) { Rl[k] = Rl[k + 2]; Rh[k] = Rh[k + 2]; }
    ihb += 2;
  }
}

// ---- Einsum: out[b,p,o] = sum_i A[b,p,i] * W[i,o,p], per spatial position p ----
__global__ __launch_bounds__(256) void k_einsum(const float* __restrict__ subs,
                                               const float* __restrict__ w1,
                                               const float* __restrict__ w2,
                                               const float* __restrict__ w3,
                                               const float* __restrict__ w4,
                                               const float* __restrict__ wt,
                                               float* __restrict__ eout,
                                               int use_wt) {
  __shared__ float sW[4096];  // [i][o]
  __shared__ float sA[2048];  // [b][i]
  int p = blockIdx.x;   // 0..1023 = h*32+w
  int s = blockIdx.y;   // subband
  int t = threadIdx.x;
  const float* A = subs + (size_t)s * 2097152;
  if (use_wt) {
    const float* Wp = wt + (size_t)s * 4194304 + (size_t)p * 4096;
#pragma unroll
    for (int k = 0; k < 16; ++k) sW[t + 256 * k] = Wp[t + 256 * k];
  } else {
    const float* Ws = (s == 0) ? w1 : (s == 1) ? w2 : (s == 2) ? w3 : w4;
#pragma unroll
    for (int k = 0; k < 16; ++k) {
      int e = t + 256 * k;
      sW[e] = Ws[e * 1024 + p];
    }
  }
#pragma unroll
  for (int k = 0; k < 8; ++k) {
    int e = t + 256 * k;                       // e = b*64 + i
    sA[e] = A[(e >> 6) * 65536 + (p << 6) + (e & 63)];
  }
  __syncthreads();
  int o  = t & 63;
  int bg = t >> 6;  // 0..3, handles b = bg*8 .. bg*8+7
  float acc[8] = {0.f, 0.f, 0.f, 0.f, 0.f, 0.f, 0.f, 0.f};
  for (int i = 0; i < 64; ++i) {
    float wv = sW[(i << 6) + o];
#pragma unroll
    for (int k = 0; k < 8; ++k) acc[k] += sA[((bg * 8 + k) << 6) + i] * wv;
  }
  float* Oo = eout + (size_t)s * 2097152 + (p << 6) + o;
#pragma unroll
  for (int k = 0; k < 8; ++k) Oo[(bg * 8 + k) * 65536] = acc[k];
}

// ---- Fused inverse: 4 subbands eout (32,32,32,64) -> out (32,128,128,64) ----
__global__ __launch_bounds__(256) void k_invfinal(const float* __restrict__ eout,
                                                  float* __restrict__ out) {
  __shared__ float4 sRes[3][2][20][16];   // 30720 B
  int t = threadIdx.x;
  int c4 = t & 15;
  int ql = t >> 4;                  // 0..15
  int bid = blockIdx.x;             // b*16 + yt*4 + xt
  int xt = bid & 3;
  int yt = (bid >> 2) & 3;
  int b  = bid >> 4;
  int q0 = xt * 16;                 // final-q base (out cols 2q0..2q0+31)
  int qi0 = (q0 >> 1) - 1;          // invres-q base (10 slots)
  int qi = qi0 + ql;                // valid work for ql < 10
  int r0p = yt * 8;                 // first emitted res-pair index

  auto loadrowI = [&](int m, float4& ae, float4& ao, float4& be, float4& bo) {
    ae = f4z(); ao = f4z(); be = f4z(); bo = f4z();
    if ((unsigned)m >= 32u) return;
    const float* base = eout + ((((size_t)b * 32 + m) * 32) << 6) + (c4 << 2);
    float4 vf[4], vl[4], vh[4], vv[4];
#pragma unroll
    for (int dn = -1; dn <= 2; ++dn) {
      int n = qi + dn;
      int nc = min(max(n, 0), 31);
      const float* p = base + (nc << 6);
      vf[dn + 1] = *(const float4*)(p);
      vl[dn + 1] = *(const float4*)(p + 2097152);
      vh[dn + 1] = *(const float4*)(p + 4194304);
      vv[dn + 1] = *(const float4*)(p + 6291456);
    }
#pragma unroll
    for (int dn = -1; dn <= 2; ++dn) {
      int n = qi + dn;
      bool ok = (unsigned)n < 32u;
      float g0e = ok ? c_g0[2 * dn + 3] : 0.f, g1e = ok ? c_g1[2 * dn + 3] : 0.f;
      float g0o = ok ? c_g0[2 * dn + 2] : 0.f, g1o = ok ? c_g1[2 * dn + 2] : 0.f;
      ae = f4fma(ae, g0e, vf[dn + 1]); ae = f4fma(ae, g1e, vl[dn + 1]);
      ao = f4fma(ao, g0o, vf[dn + 1]); ao = f4fma(ao, g1o, vl[dn + 1]);
      be = f4fma(be, g0e, vh[dn + 1]); be = f4fma(be, g1e, vv[dn + 1]);
      bo = f4fma(bo, g0o, vh[dn + 1]); bo = f4fma(bo, g1o, vv[dn + 1]);
    }
  };

  float4 Ae[4], Ao[4], Be[4], Bo[4];
  int prs = r0p - 1;                // pair cursor

  auto steppair = [&]() {
    loadrowI(prs + 2, Ae[3], Ao[3], Be[3], Bo[3]);
    float4 ee = f4z(), eo = f4z(), oe = f4z(), oo = f4z();
    if ((unsigned)prs < 32u) {
#pragma unroll
      for (int dm = 0; dm < 4; ++dm) {
        float gye = c_g0[2 * dm + 1], hye = c_g1[2 * dm + 1];
        float gyo = c_g0[2 * dm],     hyo = c_g1[2 * dm];
        ee = f4fma(ee, gye, Ae[dm]); ee = f4fma(ee, hye, Be[dm]);
        eo = f4fma(eo, gye, Ao[dm]); eo = f4fma(eo, hye, Bo[dm]);
        oe = f4fma(oe, gyo, Ae[dm]); oe = f4fma(oe, hyo, Be[dm]);
        oo = f4fma(oo, gyo, Ao[dm]); oo = f4fma(oo, hyo, Bo[dm]);
      }
    }
    int slot = ((prs % 3) + 3) % 3;
    sRes[slot][0][2 * ql][c4]     = ee;
    sRes[slot][0][2 * ql + 1][c4] = eo;
    sRes[slot][1][2 * ql][c4]     = oe;
    sRes[slot][1][2 * ql + 1][c4] = oo;
#pragma unroll
    for (int k = 0; k < 3; ++k) {
      Ae[k] = Ae[k + 1]; Ao[k] = Ao[k + 1]; Be[k] = Be[k + 1]; Bo[k] = Bo[k + 1];
    }
  };

  if (ql < 10) {
    loadrowI(prs - 1, Ae[0], Ao[0], Be[0], Bo[0]);
    loadrowI(prs,     Ae[1], Ao[1], Be[1], Bo[1]);
    loadrowI(prs + 1, Ae[2], Ao[2], Be[2], Bo[2]);
  }
#pragma unroll
  for (int pk = 0; pk < 2; ++pk) {
    if (ql < 10) steppair();
    ++prs;
  }
  int q = q0 + ql;
#pragma unroll
  for (int it = 0; it < 8; ++it) {
    if (ql < 10) steppair();       // computes pair prs
    __syncthreads();
    float4 H0[5], H1[5];
#pragma unroll
    for (int mi = 0; mi < 5; ++mi) {
      int m = 2 * (prs - 1) - 1 + mi;  // res row
      int pm = m >> 1;
      int ey = m & 1;
      int slot = ((pm % 3) + 3) % 3;
      float4 h0v = f4z(), h1v = f4z();
#pragma unroll
      for (int dn = -1; dn <= 2; ++dn) {
        int n = q + dn;
        bool ok = (unsigned)n < 64u;
        float we = ok ? c_g0[2 * dn + 3] : 0.f;
        float wo = ok ? c_g0[2 * dn + 2] : 0.f;
        float4 v = sRes[slot][ey][ql + 2 + dn][c4];
        h0v = f4fma(h0v, we, v);
        h1v = f4fma(h1v, wo, v);
      }
      H0[mi] = h0v; H1[mi] = h1v;
    }
#pragma unroll
    for (int rr2 = 0; rr2 < 2; ++rr2) {
      int r = 2 * (prs - 1) + rr2;
      float4 aee = f4z(), aeo = f4z(), aoe = f4z(), aoo = f4z();
#pragma unroll
      for (int dm = 0; dm < 4; ++dm) {
        float gye = c_g0[2 * dm + 1];
        float gyo = c_g0[2 * dm];
        aee = f4fma(aee, gye, H0[rr2 + dm]);
        aeo = f4fma(aeo, gye, H1[rr2 + dm]);
        aoe = f4fma(aoe, gyo, H0[rr2 + dm]);
        aoo = f4fma(aoo, gyo, H1[rr2 + dm]);
      }
      int y = 2 * r, xx = 2 * q;
      float* ob = out + (((size_t)(b * 128 + y)) * 128 + xx) * 64 + (c4 << 2);
      *(float4*)(ob)              = aee;
      *(float4*)(ob + 64)         = aeo;
      *(float4*)(ob + 8192)       = aoe;
      *(float4*)(ob + 8192 + 64)  = aoo;
    }
    __syncthreads();
    ++prs;
  }
}

extern "C" void kernel_launch(void* const* d_in, const int* in_sizes, int n_in,
                              void* d_out, int out_size, void* d_ws, size_t ws_size,
                              hipStream_t stream) {
  (void)in_sizes; (void)n_in; (void)out_size;
  const float* x  = (const float*)d_in[0];
  const float* w1 = (const float*)d_in[1];
  const float* w2 = (const float*)d_in[2];
  const float* w3 = (const float*)d_in[3];
  const float* w4 = (const float*)d_in[4];
  float* out = (float*)d_out;
  float* ws  = (float*)d_ws;

  // Workspace layout (floats):
  //   [0,        8388608)  ll1
  //   [8388608, 16777216)  subs (4 x 2097152)
  //   [16777216,25165824)  eout (4 x 2097152)
  //   [25165824,41943040)  wt (4 x 4194304), optional
  float* ll1  = ws;
  float* subs = ws + 8388608;
  float* eout = ws + 16777216;
  float* wt   = ws + 25165824;
  int use_wt = (ws_size >= (size_t)41943040 * 4) ? 1 : 0;

  int g1 = use_wt ? (512 + 4096) : 512;
  k_dwt1t<<<g1, 256, 0, stream>>>(x, ll1, w1, w2, w3, w4, wt);
  k_dwt2<<<512, 256, 0, stream>>>(ll1, subs);
  k_einsum<<<dim3(1024, 4), 256, 0, stream>>>(subs, w1, w2, w3, w4, wt, eout, use_wt);
  k_invfinal<<<512, 256, 0, stream>>>(eout, out);
}